// Round 4
// baseline (5958.397 us; speedup 1.0000x reference)
//
#include <hip/hip_runtime.h>
#include <stdint.h>

typedef unsigned short u16;
typedef unsigned long long u64;
typedef __attribute__((ext_vector_type(8))) short bh8;        // 8 bf16 raw (4 VGPRs)
typedef __attribute__((ext_vector_type(8))) unsigned short u16x8;
typedef __attribute__((ext_vector_type(4))) float f32x4;
typedef __attribute__((ext_vector_type(4))) unsigned int u32x4;

#define B_ 32
#define T_ 1000
#define D_ 512
#define NG 2048   // 4*D

__device__ __forceinline__ float bf2f(u16 u) {
  union { unsigned int i; float f; } v; v.i = ((unsigned int)u) << 16; return v.f;
}
__device__ __forceinline__ u16 f2bf(float f) {
  union { float f; unsigned int i; } v; v.f = f;
  return (u16)((v.i + 0x7fffu + ((v.i >> 16) & 1u)) >> 16);   // RNE
}

// ---------------- weight transpose + f32->bf16 : dst[C][R] = src[R][C] ----------------
__global__ __launch_bounds__(256) void wtrans_k(const float* __restrict__ src,
                                                u16* __restrict__ dst, int R, int C) {
  __shared__ float tile[32][33];
  const int r0 = blockIdx.x * 32, c0 = blockIdx.y * 32;
  const int tid = threadIdx.x;
#pragma unroll
  for (int q = 0; q < 4; q++) {
    int idx = q * 256 + tid, rr = idx >> 5, cc = idx & 31;
    tile[rr][cc] = src[(size_t)(r0 + rr) * C + c0 + cc];
  }
  __syncthreads();
#pragma unroll
  for (int q = 0; q < 4; q++) {
    int idx = q * 256 + tid, cc = idx >> 5, rr = idx & 31;
    dst[(size_t)(c0 + cc) * R + r0 + rr] = f2bf(tile[rr][cc]);
  }
}

__global__ void bsum_k(const float* __restrict__ a, const float* __restrict__ b,
                       float* __restrict__ o) {
  int i = blockIdx.x * blockDim.x + threadIdx.x;
  if (i < NG) o[i] = a[i] + b[i];
}

// ---------------- x[:, 0:512] = emb[zi[b][t-1]] (0 for t==0), rows ordered (t,b) ----------------
__global__ __launch_bounds__(256) void embed_k(const int* __restrict__ zi,
                                               const float* __restrict__ emb,
                                               u16* __restrict__ x) {
  const int tid = threadIdx.x;
  const int r = blockIdx.x * 4 + (tid >> 6);        // (t*32+b), grid 8000
  const int d0 = (tid & 63) * 8;
  const int t = r >> 5, b = r & 31;
  u16x8 o;
  if (t == 0) {
#pragma unroll
    for (int i = 0; i < 8; i++) o[i] = 0;
  } else {
    const int zv = zi[b * T_ + t - 1];
    const float* s = emb + (size_t)zv * D_ + d0;
#pragma unroll
    for (int i = 0; i < 8; i++) o[i] = f2bf(s[i]);
  }
  *(u16x8*)(x + (size_t)r * 1024 + d0) = o;
}

// ---------------- x[:, 512:1024] = c[b][d][t] transposed (LDS tile) ----------------
__global__ __launch_bounds__(256) void ctrans_k(const float* __restrict__ c,
                                                u16* __restrict__ x) {
  __shared__ float tile[32][65];
  const int b = blockIdx.z, d0 = blockIdx.y * 32, t0 = blockIdx.x * 64;
  const int tid = threadIdx.x;
  const int dd = tid >> 3, tt0 = (tid & 7) * 8;
  const float* src = c + ((size_t)b * D_ + d0 + dd) * T_ + t0 + tt0;
#pragma unroll
  for (int i = 0; i < 8; i++) {
    int tt = tt0 + i;
    tile[dd][tt] = (t0 + tt < T_) ? src[i] : 0.f;
  }
  __syncthreads();
  const int tt = tid & 63, dq = tid >> 6;
  if (t0 + tt < T_) {
    u16x8 o;
#pragma unroll
    for (int i = 0; i < 8; i++) o[i] = f2bf(tile[dq * 8 + i][tt]);
    *(u16x8*)(x + ((size_t)(t0 + tt) * 32 + b) * 1024 + 512 + d0 + dq * 8) = o;
  }
}

// ---------------- bf16 MFMA GEMM: C[M,N] = act(A[M,K] @ Bt[N,K]^T + bias) ----------------
template <bool RELU, bool SCATTER>
__global__ __launch_bounds__(256, 2) void gemm_k(const u16* __restrict__ A,
                                                 const u16* __restrict__ Bt,
                                                 const float* __restrict__ bias,
                                                 void* __restrict__ Cout,
                                                 int M, int N, int K) {
  __shared__ u16 Al[128 * 40];
  __shared__ u16 Bl[128 * 40];
  const int tid = threadIdx.x;
  const int w = tid >> 6, l = tid & 63;
  const int row0 = blockIdx.x * 128, col0 = blockIdx.y * 128;
  const int wr = (w >> 1) * 64, wc = (w & 1) * 64;
  f32x4 acc[4][4];
  const f32x4 zero = {0.f, 0.f, 0.f, 0.f};
#pragma unroll
  for (int i = 0; i < 4; i++)
#pragma unroll
    for (int j = 0; j < 4; j++) acc[i][j] = zero;

  const int sm = tid >> 2;
  const int sk = (tid & 3) * 8;
  const u16* Ap = A + (size_t)(row0 + sm) * K + sk;
  const u16* Bp = Bt + (size_t)(col0 + sm) * K + sk;
  const size_t half = (size_t)64 * K;
  const int ldo = sm * 40 + sk;
  const int lr = l & 15, lk = (l >> 4) * 8;
  const int KT = K >> 5;

  bh8 a0 = *(const bh8*)Ap, a1 = *(const bh8*)(Ap + half);
  bh8 b0 = *(const bh8*)Bp, b1 = *(const bh8*)(Bp + half);

  for (int kt = 0; kt < KT; kt++) {
    const int kn = (kt + 1 < KT) ? (kt + 1) * 32 : 0;
    bh8 na0 = *(const bh8*)(Ap + kn), na1 = *(const bh8*)(Ap + half + kn);
    bh8 nb0 = *(const bh8*)(Bp + kn), nb1 = *(const bh8*)(Bp + half + kn);
    *(bh8*)(Al + ldo) = a0;
    *(bh8*)(Al + ldo + 64 * 40) = a1;
    *(bh8*)(Bl + ldo) = b0;
    *(bh8*)(Bl + ldo + 64 * 40) = b1;
    __syncthreads();
    bh8 af[4], bfr[4];
#pragma unroll
    for (int i = 0; i < 4; i++) af[i] = *(const bh8*)(Al + (wr + i * 16 + lr) * 40 + lk);
#pragma unroll
    for (int j = 0; j < 4; j++) bfr[j] = *(const bh8*)(Bl + (wc + j * 16 + lr) * 40 + lk);
#pragma unroll
    for (int i = 0; i < 4; i++)
#pragma unroll
      for (int j = 0; j < 4; j++)
        acc[i][j] = __builtin_amdgcn_mfma_f32_16x16x32_bf16(af[i], bfr[j], acc[i][j], 0, 0, 0);
    __syncthreads();
    a0 = na0; a1 = na1; b0 = nb0; b1 = nb1;
  }

  const int lrow = (l >> 4) * 4;
#pragma unroll
  for (int j = 0; j < 4; j++) {
    const int n = col0 + wc + j * 16 + lr;
    const float bv = bias[n];
#pragma unroll
    for (int i = 0; i < 4; i++) {
      const int r = row0 + wr + i * 16 + lrow;
      if (SCATTER) {  // out[b][n][t], r = b*T_+t
        const int bb = r / T_;
        const int t = r - bb * T_;
        f32x4 o;
#pragma unroll
        for (int e = 0; e < 4; e++) o[e] = acc[i][j][e] + bv;
        *(f32x4*)((float*)Cout + ((size_t)bb * N + n) * T_ + t) = o;
      } else {
#pragma unroll
        for (int e = 0; e < 4; e++) {
          float v = acc[i][j][e] + bv;
          if (RELU) v = v > 0.f ? v : 0.f;
          ((u16*)Cout)[(size_t)(r + e) * N + n] = f2bf(v);
        }
      }
    }
  }
}

// ---------------- LSTM scan v4: atomic-swap push (forces LLC visibility) ----------------
// 2 groups x 16 batches; 16 wgs/group, wg owns 32 h-dims (128 gate cols, 128 weight VGPRs).
// Writer waves 0-1: pointwise -> global_atomic_swap_x2 (tag|h1|h0) -> hs store -> xg prefetch.
// Reader waves 2-3: relaxed-load tag poll (32 qwords in flight) -> stage MFMA A-frags in LDS.
__global__ __launch_bounds__(256, 1) void scan_k(const u16* __restrict__ xg,   // [T*B][2048] rows (t,b)
                                                 const u16* __restrict__ Whht, // [2048][512]
                                                 u16* __restrict__ hs,         // [B][T][512]
                                                 u64* hbuf) {                  // [2][2][16][256] tagged qwords
  __shared__ u16 hstage[16 * 512];        // 16 A-frags x (64 lanes x 8 bf16) = 16 KB
  __shared__ float gl[16][129];           // [batch][gate*32 + dim]
  const int tid = threadIdx.x;
  const int wgid = blockIdx.x;
  const int grp = wgid >> 4;              // 0..1   (16 batches each)
  const int wgin = wgid & 15;             // 0..15  (32 h-dims each)
  const int D0 = wgin * 32;
  const int bbase = grp * 16;
  const int w = tid >> 6, l = tid & 63;
  const int lr = l & 15, lc = l >> 4;
  const int lk8 = lc * 8;

  // loop-invariant B fragments: wave w = gate w, cols [D0, D0+32) -> 2 N-tiles (128 VGPRs)
  bh8 bfr[2][16];
#pragma unroll
  for (int nt = 0; nt < 2; nt++) {
    const u16* wp = Whht + (size_t)(w * 512 + D0 + nt * 16 + lr) * 512 + lk8;
#pragma unroll
    for (int kk = 0; kk < 16; kk++) bfr[nt][kk] = *(const bh8*)(wp + kk * 32);
  }

  // h_{-1} = 0
  for (int i = tid; i < 16 * 256; i += 256) ((unsigned int*)hstage)[i] = 0u;

  const int pb = tid >> 3, pd = tid & 7;   // pointwise: batch-in-group, dim-block (tid < 128)
  const int gb = bbase + pb;               // global batch
  float cc[4] = {0.f, 0.f, 0.f, 0.f};
  u64 xq[4];
  if (tid < 128) {
    const u16* xp = xg + (size_t)gb * NG + D0 + pd * 4;      // t = 0 rows
#pragma unroll
    for (int g = 0; g < 4; g++) xq[g] = *(const u64*)(xp + g * 512);
  }
  __syncthreads();

  for (int t = 0; t < T_; t++) {
    // ---- gates = h_{t-1} @ Whh : 2 N-tiles per wave, K=512, 2-way split chains ----
    f32x4 e0 = {0.f, 0.f, 0.f, 0.f}, o0 = e0, e1 = e0, o1 = e0;
#pragma unroll
    for (int kk = 0; kk < 16; kk += 2) {
      bh8 af0 = *(const bh8*)(hstage + (kk + 0) * 512 + l * 8);
      bh8 af1 = *(const bh8*)(hstage + (kk + 1) * 512 + l * 8);
      e0 = __builtin_amdgcn_mfma_f32_16x16x32_bf16(af0, bfr[0][kk + 0], e0, 0, 0, 0);
      e1 = __builtin_amdgcn_mfma_f32_16x16x32_bf16(af0, bfr[1][kk + 0], e1, 0, 0, 0);
      o0 = __builtin_amdgcn_mfma_f32_16x16x32_bf16(af1, bfr[0][kk + 1], o0, 0, 0, 0);
      o1 = __builtin_amdgcn_mfma_f32_16x16x32_bf16(af1, bfr[1][kk + 1], o1, 0, 0, 0);
    }
    const f32x4 acc0 = e0 + o0, acc1 = e1 + o1;
#pragma unroll
    for (int e = 0; e < 4; e++) {
      gl[lc * 4 + e][w * 32 + lr] = acc0[e];
      gl[lc * 4 + e][w * 32 + 16 + lr] = acc1[e];
    }
    __syncthreads();                                        // B1

    if (tid < 128) {
      // ---- pointwise: 4 dims (D0+4pd .. +3), batch gb ----
      float hv[4];
#pragma unroll
      for (int j = 0; j < 4; j++) {
        const float gi = gl[pb][ 0 + pd * 4 + j] + bf2f((u16)(xq[0] >> (16 * j)));
        const float gf = gl[pb][32 + pd * 4 + j] + bf2f((u16)(xq[1] >> (16 * j)));
        const float gg = gl[pb][64 + pd * 4 + j] + bf2f((u16)(xq[2] >> (16 * j)));
        const float go = gl[pb][96 + pd * 4 + j] + bf2f((u16)(xq[3] >> (16 * j)));
        const float si = 1.f / (1.f + __expf(-gi));
        const float sf = 1.f / (1.f + __expf(-gf));
        const float tg = 1.f - 2.f / (__expf(2.f * gg) + 1.f);
        const float so = 1.f / (1.f + __expf(-go));
        cc[j] = sf * cc[j] + si * tg;
        hv[j] = so * (1.f - 2.f / (__expf(2.f * cc[j]) + 1.f));
      }
      const unsigned int pk0 = ((unsigned int)f2bf(hv[1]) << 16) | (unsigned int)f2bf(hv[0]);
      const unsigned int pk1 = ((unsigned int)f2bf(hv[3]) << 16) | (unsigned int)f2bf(hv[2]);
      if (t + 1 < T_) {   // RMW push: executes at LLC -> promptly visible device-wide
        const u64 tag = (u64)(t + 1) << 48;
        u64* hb = hbuf + ((size_t)(((t & 1) * 2 + grp) * 16 + pb)) * 256 + D0 / 2 + pd * 2;
        (void)__hip_atomic_exchange(hb + 0, tag | (u64)pk0, __ATOMIC_RELAXED, __HIP_MEMORY_SCOPE_AGENT);
        (void)__hip_atomic_exchange(hb + 1, tag | (u64)pk1, __ATOMIC_RELAXED, __HIP_MEMORY_SCOPE_AGENT);
      }
      *(u64*)(hs + ((size_t)gb * T_ + t) * 512 + D0 + pd * 4) =
          ((u64)pk1 << 32) | (u64)pk0;
      if (t + 1 < T_) {
        const u16* xp = xg + ((size_t)(t + 1) * 32 + gb) * NG + D0 + pd * 4;
#pragma unroll
        for (int g = 0; g < 4; g++) xq[g] = *(const u64*)(xp + g * 512);
      }
    } else if (t + 1 < T_) {
      // ---- waves 2-3: batched tag poll (32 qwords in flight), then stage A-frags ----
      const int kk0 = (w - 2) * 8;
      const u64 tagv = (u64)(t + 1);
      const u64* hb = hbuf + ((size_t)(((t & 1) * 2 + grp) * 16 + lr)) * 256 + lc * 4;
      u64 q[32];
      for (;;) {
#pragma unroll
        for (int s = 0; s < 8; s++)
#pragma unroll
          for (int i = 0; i < 4; i++)
            q[s * 4 + i] = __hip_atomic_load(hb + (kk0 + s) * 16 + i,
                                             __ATOMIC_RELAXED, __HIP_MEMORY_SCOPE_AGENT);
        u64 bad = 0ull;
#pragma unroll
        for (int j = 0; j < 32; j++) bad |= (q[j] >> 48) ^ tagv;
        if (!__ballot(bad != 0ull)) break;
      }
#pragma unroll
      for (int s = 0; s < 8; s++) {
        u32x4 pk4 = {(unsigned int)q[s * 4 + 0], (unsigned int)q[s * 4 + 1],
                     (unsigned int)q[s * 4 + 2], (unsigned int)q[s * 4 + 3]};
        *(u32x4*)(hstage + (size_t)(kk0 + s) * 512 + (size_t)l * 8) = pk4;
      }
    }
    __syncthreads();                                        // B2: hstage(t) ready
  }
}

extern "C" void kernel_launch(void* const* d_in, const int* in_sizes, int n_in,
                              void* d_out, int out_size, void* d_ws, size_t ws_size,
                              hipStream_t stream) {
  const int*   zi    = (const int*)d_in[0];
  const float* c     = (const float*)d_in[1];
  const float* emb   = (const float*)d_in[2];
  const float* W1    = (const float*)d_in[3];
  const float* b1    = (const float*)d_in[4];
  const float* W2    = (const float*)d_in[5];
  const float* b2    = (const float*)d_in[6];
  const float* W_ih  = (const float*)d_in[7];
  const float* b_ih  = (const float*)d_in[8];
  const float* W_hh  = (const float*)d_in[9];
  const float* b_hh  = (const float*)d_in[10];
  const float* W_out = (const float*)d_in[11];
  const float* b_out = (const float*)d_in[12];
  float* out = (float*)d_out;
  char* ws = (char*)d_ws;

  const size_t x_off   = 0;
  const size_t xg_off  = 65536000;
  const size_t pre_off = 32768000;
  const size_t w_off   = xg_off + 131072000;
  u16* xb    = (u16*)(ws + x_off);
  u16* hsb   = (u16*)(ws + x_off);
  u16* preb  = (u16*)(ws + pre_off);
  u16* xgb   = (u16*)(ws + xg_off);
  u16* h1b   = (u16*)(ws + xg_off);
  u16* W1t   = (u16*)(ws + w_off);           // [512][1024]
  u16* W2t   = W1t + 512 * 1024;             // [512][512]
  u16* Wiht  = W2t + 512 * 512;              // [2048][512]
  u16* Whht  = Wiht + 2048 * 512;            // [2048][512]
  u16* Woutt = Whht + 2048 * 512;            // [512][512]
  float* bsum = (float*)(Woutt + 512 * 512);
  u64* hbuf  = (u64*)(bsum + NG);            // [2][2][16][256] = 128 KB

  hipMemsetAsync(hbuf, 0, 2 * 2 * 16 * 256 * sizeof(u64), stream);

  wtrans_k<<<dim3(32, 16), 256, 0, stream>>>(W1, W1t, 1024, 512);
  wtrans_k<<<dim3(16, 16), 256, 0, stream>>>(W2, W2t, 512, 512);
  wtrans_k<<<dim3(16, 64), 256, 0, stream>>>(W_ih, Wiht, 512, 2048);
  wtrans_k<<<dim3(16, 64), 256, 0, stream>>>(W_hh, Whht, 512, 2048);
  wtrans_k<<<dim3(16, 16), 256, 0, stream>>>(W_out, Woutt, 512, 512);
  bsum_k<<<8, 256, 0, stream>>>(b_ih, b_hh, bsum);
  embed_k<<<8000, 256, 0, stream>>>(zi, emb, xb);
  ctrans_k<<<dim3(16, 16, 32), 256, 0, stream>>>(c, xb);

  gemm_k<true,  false><<<dim3(250, 4),  256, 0, stream>>>(xb,   W1t,   b1,    h1b,  32000, 512,  1024);
  gemm_k<false, false><<<dim3(250, 4),  256, 0, stream>>>(h1b,  W2t,   b2,    preb, 32000, 512,  512);
  gemm_k<false, false><<<dim3(250, 16), 256, 0, stream>>>(preb, Wiht,  bsum,  xgb,  32000, 2048, 512);
  scan_k<<<32, 256, 0, stream>>>(xgb, Whht, hsb, hbuf);
  gemm_k<false, true ><<<dim3(250, 4),  256, 0, stream>>>(hsb,  Woutt, b_out, out,  32000, 512,  512);
}

// Round 5
// 3194.640 us; speedup vs baseline: 1.8651x; 1.8651x over previous
//
#include <hip/hip_runtime.h>
#include <stdint.h>

typedef unsigned short u16;
typedef unsigned int u32;
typedef unsigned long long u64;
typedef __attribute__((ext_vector_type(8))) short bh8;        // 8 bf16 raw (4 VGPRs)
typedef __attribute__((ext_vector_type(8))) unsigned short u16x8;
typedef __attribute__((ext_vector_type(4))) float f32x4;

#define B_ 32
#define T_ 1000
#define D_ 512
#define NG 2048   // 4*D

__device__ __forceinline__ float bf2f(u16 u) {
  union { unsigned int i; float f; } v; v.i = ((unsigned int)u) << 16; return v.f;
}
__device__ __forceinline__ u16 f2bf(float f) {
  union { float f; unsigned int i; } v; v.f = f;
  return (u16)((v.i + 0x7fffu + ((v.i >> 16) & 1u)) >> 16);   // RNE
}

// ---------------- weight transpose + f32->bf16 : dst[C][R] = src[R][C] ----------------
__global__ __launch_bounds__(256) void wtrans_k(const float* __restrict__ src,
                                                u16* __restrict__ dst, int R, int C) {
  __shared__ float tile[32][33];
  const int r0 = blockIdx.x * 32, c0 = blockIdx.y * 32;
  const int tid = threadIdx.x;
#pragma unroll
  for (int q = 0; q < 4; q++) {
    int idx = q * 256 + tid, rr = idx >> 5, cc = idx & 31;
    tile[rr][cc] = src[(size_t)(r0 + rr) * C + c0 + cc];
  }
  __syncthreads();
#pragma unroll
  for (int q = 0; q < 4; q++) {
    int idx = q * 256 + tid, cc = idx >> 5, rr = idx & 31;
    dst[(size_t)(c0 + cc) * R + r0 + rr] = f2bf(tile[rr][cc]);
  }
}

__global__ void bsum_k(const float* __restrict__ a, const float* __restrict__ b,
                       float* __restrict__ o) {
  int i = blockIdx.x * blockDim.x + threadIdx.x;
  if (i < NG) o[i] = a[i] + b[i];
}

// ---------------- x[:, 0:512] = emb[zi[b][t-1]] (0 for t==0), rows ordered (t,b) ----------------
__global__ __launch_bounds__(256) void embed_k(const int* __restrict__ zi,
                                               const float* __restrict__ emb,
                                               u16* __restrict__ x) {
  const int tid = threadIdx.x;
  const int r = blockIdx.x * 4 + (tid >> 6);        // (t*32+b), grid 8000
  const int d0 = (tid & 63) * 8;
  const int t = r >> 5, b = r & 31;
  u16x8 o;
  if (t == 0) {
#pragma unroll
    for (int i = 0; i < 8; i++) o[i] = 0;
  } else {
    const int zv = zi[b * T_ + t - 1];
    const float* s = emb + (size_t)zv * D_ + d0;
#pragma unroll
    for (int i = 0; i < 8; i++) o[i] = f2bf(s[i]);
  }
  *(u16x8*)(x + (size_t)r * 1024 + d0) = o;
}

// ---------------- x[:, 512:1024] = c[b][d][t] transposed (LDS tile) ----------------
__global__ __launch_bounds__(256) void ctrans_k(const float* __restrict__ c,
                                                u16* __restrict__ x) {
  __shared__ float tile[32][65];
  const int b = blockIdx.z, d0 = blockIdx.y * 32, t0 = blockIdx.x * 64;
  const int tid = threadIdx.x;
  const int dd = tid >> 3, tt0 = (tid & 7) * 8;
  const float* src = c + ((size_t)b * D_ + d0 + dd) * T_ + t0 + tt0;
#pragma unroll
  for (int i = 0; i < 8; i++) {
    int tt = tt0 + i;
    tile[dd][tt] = (t0 + tt < T_) ? src[i] : 0.f;
  }
  __syncthreads();
  const int tt = tid & 63, dq = tid >> 6;
  if (t0 + tt < T_) {
    u16x8 o;
#pragma unroll
    for (int i = 0; i < 8; i++) o[i] = f2bf(tile[dq * 8 + i][tt]);
    *(u16x8*)(x + ((size_t)(t0 + tt) * 32 + b) * 1024 + 512 + d0 + dq * 8) = o;
  }
}

// ---------------- bf16 MFMA GEMM: C[M,N] = act(A[M,K] @ Bt[N,K]^T + bias) ----------------
template <bool RELU, bool SCATTER>
__global__ __launch_bounds__(256, 2) void gemm_k(const u16* __restrict__ A,
                                                 const u16* __restrict__ Bt,
                                                 const float* __restrict__ bias,
                                                 void* __restrict__ Cout,
                                                 int M, int N, int K) {
  __shared__ u16 Al[128 * 40];
  __shared__ u16 Bl[128 * 40];
  const int tid = threadIdx.x;
  const int w = tid >> 6, l = tid & 63;
  const int row0 = blockIdx.x * 128, col0 = blockIdx.y * 128;
  const int wr = (w >> 1) * 64, wc = (w & 1) * 64;
  f32x4 acc[4][4];
  const f32x4 zero = {0.f, 0.f, 0.f, 0.f};
#pragma unroll
  for (int i = 0; i < 4; i++)
#pragma unroll
    for (int j = 0; j < 4; j++) acc[i][j] = zero;

  const int sm = tid >> 2;
  const int sk = (tid & 3) * 8;
  const u16* Ap = A + (size_t)(row0 + sm) * K + sk;
  const u16* Bp = Bt + (size_t)(col0 + sm) * K + sk;
  const size_t half = (size_t)64 * K;
  const int ldo = sm * 40 + sk;
  const int lr = l & 15, lk = (l >> 4) * 8;
  const int KT = K >> 5;

  bh8 a0 = *(const bh8*)Ap, a1 = *(const bh8*)(Ap + half);
  bh8 b0 = *(const bh8*)Bp, b1 = *(const bh8*)(Bp + half);

  for (int kt = 0; kt < KT; kt++) {
    const int kn = (kt + 1 < KT) ? (kt + 1) * 32 : 0;
    bh8 na0 = *(const bh8*)(Ap + kn), na1 = *(const bh8*)(Ap + half + kn);
    bh8 nb0 = *(const bh8*)(Bp + kn), nb1 = *(const bh8*)(Bp + half + kn);
    *(bh8*)(Al + ldo) = a0;
    *(bh8*)(Al + ldo + 64 * 40) = a1;
    *(bh8*)(Bl + ldo) = b0;
    *(bh8*)(Bl + ldo + 64 * 40) = b1;
    __syncthreads();
    bh8 af[4], bfr[4];
#pragma unroll
    for (int i = 0; i < 4; i++) af[i] = *(const bh8*)(Al + (wr + i * 16 + lr) * 40 + lk);
#pragma unroll
    for (int j = 0; j < 4; j++) bfr[j] = *(const bh8*)(Bl + (wc + j * 16 + lr) * 40 + lk);
#pragma unroll
    for (int i = 0; i < 4; i++)
#pragma unroll
      for (int j = 0; j < 4; j++)
        acc[i][j] = __builtin_amdgcn_mfma_f32_16x16x32_bf16(af[i], bfr[j], acc[i][j], 0, 0, 0);
    __syncthreads();
    a0 = na0; a1 = na1; b0 = nb0; b1 = nb1;
  }

  const int lrow = (l >> 4) * 4;
#pragma unroll
  for (int j = 0; j < 4; j++) {
    const int n = col0 + wc + j * 16 + lr;
    const float bv = bias[n];
#pragma unroll
    for (int i = 0; i < 4; i++) {
      const int r = row0 + wr + i * 16 + lrow;
      if (SCATTER) {  // out[b][n][t], r = b*T_+t
        const int bb = r / T_;
        const int t = r - bb * T_;
        f32x4 o;
#pragma unroll
        for (int e = 0; e < 4; e++) o[e] = acc[i][j][e] + bv;
        *(f32x4*)((float*)Cout + ((size_t)bb * N + n) * T_ + t) = o;
      } else {
#pragma unroll
        for (int e = 0; e < 4; e++) {
          float v = acc[i][j][e] + bv;
          if (RELU) v = v > 0.f ? v : 0.f;
          ((u16*)Cout)[(size_t)(r + e) * N + n] = f2bf(v);
        }
      }
    }
  }
}

// ---- sc0 (SE-scope: bypass L1, hit local L2) / sc1 (agent: coherence point) poll ----
__device__ __forceinline__ void poll8(const u32* p, u64 q[8], bool slow) {
  const u64 a = (u64)(uintptr_t)p;
  if (!slow) {
    asm volatile(
        "global_load_dwordx2 %0, %8, off sc0\n\t"
        "global_load_dwordx2 %1, %8, off offset:256 sc0\n\t"
        "global_load_dwordx2 %2, %8, off offset:512 sc0\n\t"
        "global_load_dwordx2 %3, %8, off offset:768 sc0\n\t"
        "global_load_dwordx2 %4, %8, off offset:1024 sc0\n\t"
        "global_load_dwordx2 %5, %8, off offset:1280 sc0\n\t"
        "global_load_dwordx2 %6, %8, off offset:1536 sc0\n\t"
        "global_load_dwordx2 %7, %8, off offset:1792 sc0\n\t"
        "s_waitcnt vmcnt(0)"
        : "=&v"(q[0]), "=&v"(q[1]), "=&v"(q[2]), "=&v"(q[3]),
          "=&v"(q[4]), "=&v"(q[5]), "=&v"(q[6]), "=&v"(q[7])
        : "v"(a)
        : "memory");
  } else {
    asm volatile(
        "global_load_dwordx2 %0, %8, off sc1\n\t"
        "global_load_dwordx2 %1, %8, off offset:256 sc1\n\t"
        "global_load_dwordx2 %2, %8, off offset:512 sc1\n\t"
        "global_load_dwordx2 %3, %8, off offset:768 sc1\n\t"
        "global_load_dwordx2 %4, %8, off offset:1024 sc1\n\t"
        "global_load_dwordx2 %5, %8, off offset:1280 sc1\n\t"
        "global_load_dwordx2 %6, %8, off offset:1536 sc1\n\t"
        "global_load_dwordx2 %7, %8, off offset:1792 sc1\n\t"
        "s_waitcnt vmcnt(0)"
        : "=&v"(q[0]), "=&v"(q[1]), "=&v"(q[2]), "=&v"(q[3]),
          "=&v"(q[4]), "=&v"(q[5]), "=&v"(q[6]), "=&v"(q[7])
        : "v"(a)
        : "memory");
  }
}

// ---------------- LSTM scan v5: XCD-local sync ----------------
// 8 groups x 4 batches, group g = wgs {wgid&7==g} (round-robin dispatch -> one XCD/group).
// 32 wgs/group, wg owns 16 h-dims (64 gate cols). Exchange: tagged u32 (tag16|bf16) per dim.
// Fast path: sc0 store + sc0 poll through the XCD's L2. Shadow path (placement-independent
// correctness): agent-scope atomic exchange + sc1 poll, sticky fallback after 256 rounds.
__global__ __launch_bounds__(256, 1) void scan_k(const u16* __restrict__ xg,   // [T*B][2048] rows (t,b)
                                                 const u16* __restrict__ Whht, // [2048][512]
                                                 u16* __restrict__ hs,         // [B][T][512]
                                                 u32* hbuf) {                  // fast[2][8][4][512] + slow[...]
  __shared__ u16 hstage[16 * 512];        // 16 A-frags (K=512), rows 0-3 = batches, rest zero
  __shared__ float gl[4][68];             // [batch][gate*16 + dim]
  const int tid = threadIdx.x;
  const int wgid = blockIdx.x;
  const int grp = wgid & 7;               // XCD id under round-robin dispatch
  const int wgin = wgid >> 3;             // 0..31 within group
  const int D0 = wgin * 16;
  const int w = tid >> 6, l = tid & 63;
  const int lr = l & 15, lc = l >> 4;

  u32* fb = hbuf;                         // fast: [2][8][4][512] u32 = 128 KB
  u32* sb = hbuf + 32768;                 // slow shadow, same layout

  // loop-invariant B fragments: wave w = gate w, cols D0..D0+15 (64 VGPRs)
  bh8 bfr[16];
  {
    const u16* wp = Whht + (size_t)(w * 512 + D0 + lr) * 512 + lc * 8;
#pragma unroll
    for (int kk = 0; kk < 16; kk++) bfr[kk] = *(const bh8*)(wp + kk * 32);
  }

  // h_{-1} = 0 (rows >=4 of every frag stay zero forever)
  for (int i = tid; i < 16 * 256; i += 256) ((u32*)hstage)[i] = 0u;

  // writer mapping (wave 0): lane -> (batch b, dim d)
  const int pb = l >> 4, pd = l & 15;
  const int gbat = grp * 4 + pb;
  float ccv = 0.f;
  u16 xh[4];
  if (w == 0) {
    const u16* xp = xg + (size_t)gbat * NG + D0 + pd;        // t = 0 rows
#pragma unroll
    for (int g = 0; g < 4; g++) xh[g] = xp[g * 512];
  }
  // reader mapping (waves 2,3): lane -> (batch rb, dim-pair column l5)
  const int rb = (w - 2) * 2 + (l >> 5);
  const int l5 = l & 31;
  bool slowmode = false;
  __syncthreads();

  for (int t = 0; t < T_; t++) {
    // ---- gates = h_{t-1} @ Whh : one M=4,N=16 tile per wave, K=512 ----
    f32x4 e0 = {0.f, 0.f, 0.f, 0.f}, e1 = e0;
#pragma unroll
    for (int kk = 0; kk < 16; kk += 2) {
      bh8 af0 = *(const bh8*)(hstage + (kk + 0) * 512 + l * 8);
      bh8 af1 = *(const bh8*)(hstage + (kk + 1) * 512 + l * 8);
      e0 = __builtin_amdgcn_mfma_f32_16x16x32_bf16(af0, bfr[kk + 0], e0, 0, 0, 0);
      e1 = __builtin_amdgcn_mfma_f32_16x16x32_bf16(af1, bfr[kk + 1], e1, 0, 0, 0);
    }
    const f32x4 acc = e0 + e1;
    if (lc == 0) {                        // rows 0-3 = batches
#pragma unroll
      for (int e = 0; e < 4; e++) gl[e][w * 16 + lr] = acc[e];
    }
    __syncthreads();                                        // B1

    if (w == 0) {
      // ---- pointwise: one h-value per lane (batch pb, dim D0+pd) ----
      const float gi = gl[pb][ 0 + pd] + bf2f(xh[0]);
      const float gf = gl[pb][16 + pd] + bf2f(xh[1]);
      const float gg = gl[pb][32 + pd] + bf2f(xh[2]);
      const float go = gl[pb][48 + pd] + bf2f(xh[3]);
      const float si = 1.f / (1.f + __expf(-gi));
      const float sf = 1.f / (1.f + __expf(-gf));
      const float tg = 1.f - 2.f / (__expf(2.f * gg) + 1.f);
      const float so = 1.f / (1.f + __expf(-go));
      ccv = sf * ccv + si * tg;
      const float hv = so * (1.f - 2.f / (__expf(2.f * ccv) + 1.f));
      const u16 hb = f2bf(hv);
      if (t + 1 < T_) {
        const u32 tagged = ((u32)(t + 1) << 16) | (u32)hb;
        const size_t idx = ((size_t)((t & 1) * 8 + grp) * 4 + pb) * 512 + D0 + pd;
        asm volatile("global_store_dword %0, %1, off sc0"
                     :: "v"((u64)(uintptr_t)(fb + idx)), "v"(tagged) : "memory");
        (void)__hip_atomic_exchange(sb + idx, tagged, __ATOMIC_RELAXED,
                                    __HIP_MEMORY_SCOPE_AGENT);
      }
      hs[((size_t)gbat * T_ + t) * 512 + D0 + pd] = hb;
      if (t + 1 < T_) {
        const u16* xp = xg + ((size_t)(t + 1) * 32 + gbat) * NG + D0 + pd;
#pragma unroll
        for (int g = 0; g < 4; g++) xh[g] = xp[g * 512];
      }
    } else if (w >= 2 && t + 1 < T_) {
      // ---- readers: poll 8 dim-pairs (batch rb, dims 2*l5+64s, +1), stage A-frags ----
      const u32 tag = (u32)(t + 1);
      const size_t base = ((size_t)((t & 1) * 8 + grp) * 4 + rb) * 512 + 2 * l5;
      u64 q[8];
      int rounds = 0;
      for (;;) {
        poll8(fb + base, q, false);
        if (slowmode) poll8(sb + base, q, true);
        u32 bad = 0;
#pragma unroll
        for (int s = 0; s < 8; s++) {
          bad |= ((u32)q[s] >> 16) ^ tag;
          bad |= ((u32)(q[s] >> 32) >> 16) ^ tag;
        }
        if (!__ballot(bad != 0u)) break;
        if (++rounds > 256) slowmode = true;
      }
#pragma unroll
      for (int s = 0; s < 8; s++) {
        const int k = 2 * l5 + 64 * s;
        const u32 wv = ((u32)q[s] & 0xffffu) | ((u32)(q[s] >> 32) << 16);
        *(u32*)(hstage + (k >> 5) * 512 + (rb + ((k >> 3) & 3) * 16) * 8 + (k & 7)) = wv;
      }
    }
    __syncthreads();                                        // B2: hstage(t) ready
  }
}

extern "C" void kernel_launch(void* const* d_in, const int* in_sizes, int n_in,
                              void* d_out, int out_size, void* d_ws, size_t ws_size,
                              hipStream_t stream) {
  const int*   zi    = (const int*)d_in[0];
  const float* c     = (const float*)d_in[1];
  const float* emb   = (const float*)d_in[2];
  const float* W1    = (const float*)d_in[3];
  const float* b1    = (const float*)d_in[4];
  const float* W2    = (const float*)d_in[5];
  const float* b2    = (const float*)d_in[6];
  const float* W_ih  = (const float*)d_in[7];
  const float* b_ih  = (const float*)d_in[8];
  const float* W_hh  = (const float*)d_in[9];
  const float* b_hh  = (const float*)d_in[10];
  const float* W_out = (const float*)d_in[11];
  const float* b_out = (const float*)d_in[12];
  float* out = (float*)d_out;
  char* ws = (char*)d_ws;

  const size_t x_off   = 0;
  const size_t xg_off  = 65536000;
  const size_t pre_off = 32768000;
  const size_t w_off   = xg_off + 131072000;
  u16* xb    = (u16*)(ws + x_off);
  u16* hsb   = (u16*)(ws + x_off);
  u16* preb  = (u16*)(ws + pre_off);
  u16* xgb   = (u16*)(ws + xg_off);
  u16* h1b   = (u16*)(ws + xg_off);
  u16* W1t   = (u16*)(ws + w_off);           // [512][1024]
  u16* W2t   = W1t + 512 * 1024;             // [512][512]
  u16* Wiht  = W2t + 512 * 512;              // [2048][512]
  u16* Whht  = Wiht + 2048 * 512;            // [2048][512]
  u16* Woutt = Whht + 2048 * 512;            // [512][512]
  float* bsum = (float*)(Woutt + 512 * 512);
  u32* hbuf  = (u32*)(bsum + NG);            // fast 128KB + slow 128KB

  hipMemsetAsync(hbuf, 0, 2 * 2 * 8 * 4 * 512 * sizeof(u32), stream);

  wtrans_k<<<dim3(32, 16), 256, 0, stream>>>(W1, W1t, 1024, 512);
  wtrans_k<<<dim3(16, 16), 256, 0, stream>>>(W2, W2t, 512, 512);
  wtrans_k<<<dim3(16, 64), 256, 0, stream>>>(W_ih, Wiht, 512, 2048);
  wtrans_k<<<dim3(16, 64), 256, 0, stream>>>(W_hh, Whht, 512, 2048);
  wtrans_k<<<dim3(16, 16), 256, 0, stream>>>(W_out, Woutt, 512, 512);
  bsum_k<<<8, 256, 0, stream>>>(b_ih, b_hh, bsum);
  embed_k<<<8000, 256, 0, stream>>>(zi, emb, xb);
  ctrans_k<<<dim3(16, 16, 32), 256, 0, stream>>>(c, xb);

  gemm_k<true,  false><<<dim3(250, 4),  256, 0, stream>>>(xb,   W1t,   b1,    h1b,  32000, 512,  1024);
  gemm_k<false, false><<<dim3(250, 4),  256, 0, stream>>>(h1b,  W2t,   b2,    preb, 32000, 512,  512);
  gemm_k<false, false><<<dim3(250, 16), 256, 0, stream>>>(preb, Wiht,  bsum,  xgb,  32000, 2048, 512);
  scan_k<<<256, 256, 0, stream>>>(xgb, Whht, hsb, hbuf);
  gemm_k<false, true ><<<dim3(250, 4),  256, 0, stream>>>(hsb,  Woutt, b_out, out,  32000, 512,  512);
}